// Round 2
// baseline (759.174 us; speedup 1.0000x reference)
//
#include <hip/hip_runtime.h>
#include <stdint.h>

#define NB 8192
#define DD 256

// ---------------- workspace layout ----------------
// diag   : float[8192]  @ 0
// band   : int[8192]    @ 32768   (init 0x7F7F7F7F)
// fb     : u64[8192]    @ 65536   (init 0)
// neg    : int[8192]    @ 131072
// acc    : float[1]     @ 163840  (init 0)

// ---------------- diag kernel: diag[i] = t_uni[i].v_uni[i] ----------------
__global__ __launch_bounds__(256) void diag_kernel(const float* __restrict__ t,
                                                   const float* __restrict__ v,
                                                   float* __restrict__ diag) {
    int row = blockIdx.x * 4 + (threadIdx.x >> 6);
    int lane = threadIdx.x & 63;
    float4 a = *(const float4*)(t + (size_t)row * DD + lane * 4);
    float4 b = *(const float4*)(v + (size_t)row * DD + lane * 4);
    float s = a.x * b.x + a.y * b.y + a.z * b.z + a.w * b.w;
    #pragma unroll
    for (int off = 32; off; off >>= 1) s += __shfl_down(s, off);
    if (lane == 0) diag[row] = s;
}

// ---------------- mining kernel ----------------
// S = t_uni @ v_uni^T.  Per row: min col index with (S > d-0.5 && S < d-0.2, j!=i),
// and packed argmax over off-diagonal S for the fallback.
// Grid: x = 128 row tiles (64 rows), y = 8 col chunks (1024 cols).
__global__ __launch_bounds__(256) void mine_kernel(const float* __restrict__ tuni,
                                                   const float* __restrict__ vuni,
                                                   const float* __restrict__ diag,
                                                   int* __restrict__ band_idx,
                                                   unsigned long long* __restrict__ fb) {
    __shared__ float Ts[64][68];
    __shared__ float Vs[64][68];
    __shared__ float diag_s[64];
    __shared__ int band_l[64];
    __shared__ unsigned long long fb_l[64];

    const int tid = threadIdx.x;
    const int rowBase = blockIdx.x * 64;
    const int colChunk = blockIdx.y;
    const int tx = tid & 15, ty = tid >> 4;

    if (tid < 64) {
        band_l[tid] = 0x7FFFFFFF;
        fb_l[tid] = 0ULL;
        diag_s[tid] = diag[rowBase + tid];
    }
    __syncthreads();

    for (int ct = 0; ct < 16; ++ct) {
        const int colBase = colChunk * 1024 + ct * 64;
        float acc[4][4];
        #pragma unroll
        for (int m = 0; m < 4; m++)
            #pragma unroll
            for (int n = 0; n < 4; n++) acc[m][n] = 0.f;

        for (int kc = 0; kc < DD; kc += 64) {
            __syncthreads();
            #pragma unroll
            for (int i = 0; i < 4; i++) {
                int idx = tid + i * 256;       // 0..1023
                int r = idx >> 4, c = idx & 15;
                float4 tv = *(const float4*)(tuni + (size_t)(rowBase + r) * DD + kc + c * 4);
                *(float4*)&Ts[r][c * 4] = tv;
                float4 vv = *(const float4*)(vuni + (size_t)(colBase + r) * DD + kc + c * 4);
                *(float4*)&Vs[r][c * 4] = vv;
            }
            __syncthreads();
            #pragma unroll 4
            for (int kq = 0; kq < 16; kq++) {
                float4 tq[4], vq[4];
                #pragma unroll
                for (int m = 0; m < 4; m++) tq[m] = *(const float4*)&Ts[ty + 16 * m][kq * 4];
                #pragma unroll
                for (int n = 0; n < 4; n++) vq[n] = *(const float4*)&Vs[tx + 16 * n][kq * 4];
                #pragma unroll
                for (int m = 0; m < 4; m++)
                    #pragma unroll
                    for (int n = 0; n < 4; n++) {
                        acc[m][n] += tq[m].x * vq[n].x + tq[m].y * vq[n].y +
                                     tq[m].z * vq[n].z + tq[m].w * vq[n].w;
                    }
            }
        }

        // per-row candidate reduction
        #pragma unroll
        for (int m = 0; m < 4; m++) {
            const int rl = ty + 16 * m;
            const int grow = rowBase + rl;
            const float d = diag_s[rl];
            unsigned long long pk = 0ULL;
            int bmin = 0x7FFFFFFF;
            #pragma unroll
            for (int n = 0; n < 4; n++) {
                int gcol = colBase + tx + 16 * n;
                float s = acc[m][n];
                if (gcol != grow) {
                    unsigned u = __float_as_uint(s);
                    unsigned key = (u & 0x80000000u) ? ~u : (u | 0x80000000u);
                    unsigned long long p = ((unsigned long long)key << 32) | (unsigned)gcol;
                    pk = (p > pk) ? p : pk;
                    if (s > d - 0.5f && s < d - 0.2f) bmin = min(bmin, gcol);
                }
            }
            // reduce across the 16 tx lanes sharing this row
            #pragma unroll
            for (int off = 1; off < 16; off <<= 1) {
                unsigned long long po = __shfl_xor(pk, off);
                int bo = __shfl_xor(bmin, off);
                pk = (po > pk) ? po : pk;
                bmin = min(bmin, bo);
            }
            if (tx == 0) {
                atomicMax(&fb_l[rl], pk);
                if (bmin != 0x7FFFFFFF) atomicMin(&band_l[rl], bmin);
            }
        }
    }
    __syncthreads();
    if (tid < 64) {
        int grow = rowBase + tid;
        if (band_l[tid] != 0x7FFFFFFF) atomicMin(&band_idx[grow], band_l[tid]);
        atomicMax(&fb[grow], fb_l[tid]);
    }
}

// ---------------- combine ----------------
__global__ __launch_bounds__(256) void combine_kernel(const int* __restrict__ band_idx,
                                                      const unsigned long long* __restrict__ fb,
                                                      int* __restrict__ neg) {
    int i = blockIdx.x * 256 + threadIdx.x;
    int b = band_idx[i];
    neg[i] = (b < NB) ? b : (int)(unsigned)(fb[i] & 0xFFFFFFFFull);
}

// ---------------- fused ITM head (pos + neg) + loss ----------------
__device__ __forceinline__ void fma4(float4& acc, const float4 wv, const float xs) {
    acc.x += wv.x * xs; acc.y += wv.y * xs; acc.z += wv.z * xs; acc.w += wv.w * xs;
}

__device__ __forceinline__ float rdot(float4 t, float4 a, float4 wv) {
    float h0 = fmaxf(t.x + a.x, 0.f);
    float h1 = fmaxf(t.y + a.y, 0.f);
    float h2 = fmaxf(t.z + a.z, 0.f);
    float h3 = fmaxf(t.w + a.w, 0.f);
    return h0 * wv.x + h1 * wv.y + h2 * wv.z + h3 * wv.w;
}

__global__ __launch_bounds__(256) void head_kernel(const float* __restrict__ tcross,
                                                   const float* __restrict__ vcross,
                                                   const int* __restrict__ neg,
                                                   const float* __restrict__ W1,
                                                   const float* __restrict__ b1,
                                                   const float* __restrict__ W2,
                                                   const float* __restrict__ b2,
                                                   float* __restrict__ acc_out) {
    __shared__ float tL[8][DD], vpL[8][DD], vnL[8][DD];
    __shared__ float dotp[8], dotn[8];

    const int tid = threadIdx.x;
    const int rowBase = blockIdx.x * 8;

    #pragma unroll
    for (int i = 0; i < 2; i++) {
        int idx = tid + i * 256;           // 0..511 -> 8 rows x 64 float4
        int r = idx >> 6, c = idx & 63;
        *(float4*)&tL[r][c * 4]  = *(const float4*)(tcross + (size_t)(rowBase + r) * DD + c * 4);
        *(float4*)&vpL[r][c * 4] = *(const float4*)(vcross + (size_t)(rowBase + r) * DD + c * 4);
        int nr = neg[rowBase + r];
        *(float4*)&vnL[r][c * 4] = *(const float4*)(vcross + (size_t)nr * DD + c * 4);
    }
    __syncthreads();

    const int lane = tid & 63;
    const int g = tid >> 6;      // wave id, rows 2g, 2g+1

    // dots (wave g does rows 2g, 2g+1)
    #pragma unroll
    for (int rr = 0; rr < 2; rr++) {
        int r = g * 2 + rr;
        float4 a = *(const float4*)&tL[r][lane * 4];
        float4 p = *(const float4*)&vpL[r][lane * 4];
        float4 q = *(const float4*)&vnL[r][lane * 4];
        float sp = a.x * p.x + a.y * p.y + a.z * p.z + a.w * p.w;
        float sn = a.x * q.x + a.y * q.y + a.z * q.z + a.w * q.w;
        #pragma unroll
        for (int off = 32; off; off >>= 1) {
            sp += __shfl_down(sp, off);
            sn += __shfl_down(sn, off);
        }
        if (lane == 0) { dotp[r] = sp; dotn[r] = sn; }
    }
    __syncthreads();

    // GEMM: lane u owns units 4u..4u+3; wave g owns rows r0,r1
    const int u = lane;
    const int r0 = g * 2, r1 = g * 2 + 1;
    float4 bq = *(const float4*)(b1 + 4 * u);
    float4 accT0 = bq, accT1 = bq;
    float4 aP0 = {0, 0, 0, 0}, aP1 = {0, 0, 0, 0}, aN0 = {0, 0, 0, 0}, aN1 = {0, 0, 0, 0};
    const float* W1u = W1 + 4 * u;

    #pragma unroll 4
    for (int k = 0; k < 256; k++) {           // shared t-part of x
        float4 w4 = *(const float4*)(W1u + (size_t)k * DD);
        float x0 = tL[r0][k], x1 = tL[r1][k];
        fma4(accT0, w4, x0); fma4(accT1, w4, x1);
    }
    #pragma unroll 4
    for (int k = 0; k < 256; k++) {           // v-part (pos / neg)
        float4 w4 = *(const float4*)(W1u + (size_t)(256 + k) * DD);
        float p0 = vpL[r0][k], p1 = vpL[r1][k];
        float q0 = vnL[r0][k], q1 = vnL[r1][k];
        fma4(aP0, w4, p0); fma4(aP1, w4, p1);
        fma4(aN0, w4, q0); fma4(aN1, w4, q1);
    }
    {                                          // dot feature (row 512 of W1)
        float4 w4 = *(const float4*)(W1u + (size_t)512 * DD);
        fma4(aP0, w4, dotp[r0]); fma4(aP1, w4, dotp[r1]);
        fma4(aN0, w4, dotn[r0]); fma4(aN1, w4, dotn[r1]);
    }

    float4 w2q = *(const float4*)(W2 + 4 * u);
    float pp0 = rdot(accT0, aP0, w2q);
    float pp1 = rdot(accT1, aP1, w2q);
    float pn0 = rdot(accT0, aN0, w2q);
    float pn1 = rdot(accT1, aN1, w2q);
    #pragma unroll
    for (int off = 32; off; off >>= 1) {
        pp0 += __shfl_down(pp0, off);
        pp1 += __shfl_down(pp1, off);
        pn0 += __shfl_down(pn0, off);
        pn1 += __shfl_down(pn1, off);
    }
    if (lane == 0) {
        float bb = b2[0];
        float lp0 = pp0 + bb, lp1 = pp1 + bb, ln0 = pn0 + bb, ln1 = pn1 + bb;
        float term = -logf(1.f / (1.f + expf(-lp0)) + 1e-8f)
                     -logf(1.f / (1.f + expf(-lp1)) + 1e-8f)
                     -logf(1.f / (1.f + expf(ln0)) + 1e-8f)     // 1-sigmoid(x)=sigmoid(-x)
                     -logf(1.f / (1.f + expf(ln1)) + 1e-8f);
        atomicAdd(acc_out, term);
    }
}

// ---------------- finalize ----------------
__global__ void finalize_kernel(const float* __restrict__ acc, float* __restrict__ out) {
    out[0] = acc[0] * (1.0f / (2.0f * (float)NB));
}

extern "C" void kernel_launch(void* const* d_in, const int* in_sizes, int n_in,
                              void* d_out, int out_size, void* d_ws, size_t ws_size,
                              hipStream_t stream) {
    const float* vcross = (const float*)d_in[0];
    const float* tcross = (const float*)d_in[1];
    const float* vuni   = (const float*)d_in[2];
    const float* tuni   = (const float*)d_in[3];
    const float* W1     = (const float*)d_in[4];
    const float* b1     = (const float*)d_in[5];
    const float* W2     = (const float*)d_in[6];
    const float* b2     = (const float*)d_in[7];

    char* ws = (char*)d_ws;
    float* diag = (float*)(ws);
    int* band   = (int*)(ws + 32768);
    unsigned long long* fb = (unsigned long long*)(ws + 65536);
    int* neg    = (int*)(ws + 131072);
    float* acc  = (float*)(ws + 163840);

    hipMemsetAsync(band, 0x7F, NB * sizeof(int), stream);   // 0x7F7F7F7F > any valid idx
    hipMemsetAsync(fb, 0, NB * sizeof(unsigned long long), stream);
    hipMemsetAsync(acc, 0, sizeof(float), stream);

    diag_kernel<<<NB / 4, 256, 0, stream>>>(tuni, vuni, diag);
    mine_kernel<<<dim3(NB / 64, 8), 256, 0, stream>>>(tuni, vuni, diag, band, fb);
    combine_kernel<<<NB / 256, 256, 0, stream>>>(band, fb, neg);
    head_kernel<<<NB / 8, 256, 0, stream>>>(tcross, vcross, neg, W1, b1, W2, b2, acc);
    finalize_kernel<<<1, 1, 0, stream>>>(acc, (float*)d_out);
}

// Round 3
// 238.670 us; speedup vs baseline: 3.1809x; 3.1809x over previous
//
#include <hip/hip_runtime.h>
#include <stdint.h>

#define NB 8192
#define DD 256

typedef __attribute__((ext_vector_type(8))) short bf16x8;
typedef __attribute__((ext_vector_type(4))) float f32x4;

// ==================== fast-path workspace layout ====================
// diag     f32[8192]            @ 0
// neg      int[8192]            @ 32768
// acc      f32[1]               @ 65536
// bandPart int[16][8192]        @ 131072   (512 KB)
// fbPart   u64[16][8192]        @ 655360   (1 MB)
// tb       bf16[8192][256]      @ 1703936  (4 MB)
// vb       bf16[8192][256]      @ 5898240  (4 MB)  -> end 10092544
#define WS_FAST_BYTES 10092544

// ---------------- diag kernel: diag[i] = t_uni[i].v_uni[i] (fp32) ----------------
__global__ __launch_bounds__(256) void diag_kernel(const float* __restrict__ t,
                                                   const float* __restrict__ v,
                                                   float* __restrict__ diag) {
    int row = blockIdx.x * 4 + (threadIdx.x >> 6);
    int lane = threadIdx.x & 63;
    float4 a = *(const float4*)(t + (size_t)row * DD + lane * 4);
    float4 b = *(const float4*)(v + (size_t)row * DD + lane * 4);
    float s = a.x * b.x + a.y * b.y + a.z * b.z + a.w * b.w;
    #pragma unroll
    for (int off = 32; off; off >>= 1) s += __shfl_down(s, off);
    if (lane == 0) diag[row] = s;
}

// ---------------- f32 -> bf16 convert (RNE) ----------------
__device__ __forceinline__ unsigned short f2bf(float x) {
    uint32_t u = __float_as_uint(x);
    return (unsigned short)((u + 0x7FFFu + ((u >> 16) & 1u)) >> 16);
}

__global__ __launch_bounds__(256) void cvt_kernel(const float* __restrict__ in,
                                                  unsigned short* __restrict__ out) {
    int i = blockIdx.x * 256 + threadIdx.x;      // 8 floats per thread
    const float4* p = (const float4*)(in + (size_t)i * 8);
    float4 x = p[0], y = p[1];
    uint4 o;
    o.x = (uint32_t)f2bf(x.x) | ((uint32_t)f2bf(x.y) << 16);
    o.y = (uint32_t)f2bf(x.z) | ((uint32_t)f2bf(x.w) << 16);
    o.z = (uint32_t)f2bf(y.x) | ((uint32_t)f2bf(y.y) << 16);
    o.w = (uint32_t)f2bf(y.z) | ((uint32_t)f2bf(y.w) << 16);
    *(uint4*)(out + (size_t)i * 8) = o;
}

// ---------------- MFMA mining kernel ----------------
// S = T_bf16 @ V_bf16^T. Block: 128 rows x (4 x 128 cols), K=256 in 4 steps of 64.
// Grid (64, 16). m97 structure: global_load_lds w16, linear LDS, 2-barrier K-loop.
__device__ __forceinline__ void stage_tiles(const unsigned short* __restrict__ TB,
                                            const unsigned short* __restrict__ VB,
                                            unsigned short* As, unsigned short* Bs,
                                            int rowBase, int colBase, int kc, int tid) {
    #pragma unroll
    for (int i = 0; i < 4; ++i) {
        int idx = i * 256 + tid;              // 0..1023
        int r = idx >> 3, c8 = idx & 7;       // row, 8-elem chunk
        __builtin_amdgcn_global_load_lds(
            (const __attribute__((address_space(1))) uint32_t*)(TB + (size_t)(rowBase + r) * DD + kc + c8 * 8),
            (__attribute__((address_space(3))) uint32_t*)(As + idx * 8), 16, 0, 0);
        __builtin_amdgcn_global_load_lds(
            (const __attribute__((address_space(1))) uint32_t*)(VB + (size_t)(colBase + r) * DD + kc + c8 * 8),
            (__attribute__((address_space(3))) uint32_t*)(Bs + idx * 8), 16, 0, 0);
    }
}

__global__ __launch_bounds__(256) void mine2_kernel(const unsigned short* __restrict__ TB,
                                                    const unsigned short* __restrict__ VB,
                                                    const float* __restrict__ diag,
                                                    int* __restrict__ bandPart,
                                                    unsigned long long* __restrict__ fbPart) {
    __shared__ unsigned short As[2][128 * 64];
    __shared__ unsigned short Bs[2][128 * 64];
    __shared__ float diag_s[128];
    __shared__ int band_l[128];
    __shared__ unsigned long long fb_l[128];

    const int tid = threadIdx.x;
    const int rowBase = blockIdx.x * 128;
    const int colGroup = blockIdx.y;

    const int lane = tid & 63;
    const int wave = tid >> 6;
    const int wr = wave >> 1, wc = wave & 1;   // 2x2 waves, 64x64 each
    const int lo = lane & 15, hi = lane >> 4;

    if (tid < 128) {
        band_l[tid] = 0x7FFFFFFF;
        fb_l[tid] = 0ULL;
        diag_s[tid] = diag[rowBase + tid];
    }

    for (int ct = 0; ct < 4; ++ct) {
        const int colBase = colGroup * 512 + ct * 128;
        f32x4 acc[4][4];
        #pragma unroll
        for (int m = 0; m < 4; m++)
            #pragma unroll
            for (int n = 0; n < 4; n++) acc[m][n] = (f32x4){0.f, 0.f, 0.f, 0.f};

        stage_tiles(TB, VB, As[0], Bs[0], rowBase, colBase, 0, tid);
        __syncthreads();

        for (int kt = 0; kt < 4; ++kt) {
            const int buf = kt & 1;
            if (kt < 3)
                stage_tiles(TB, VB, As[buf ^ 1], Bs[buf ^ 1], rowBase, colBase, (kt + 1) * 64, tid);
            #pragma unroll
            for (int ksl = 0; ksl < 2; ksl++) {
                bf16x8 a[4], b[4];
                #pragma unroll
                for (int m = 0; m < 4; m++)
                    a[m] = *(const bf16x8*)&As[buf][(wr * 64 + m * 16 + lo) * 64 + ksl * 32 + hi * 8];
                #pragma unroll
                for (int n = 0; n < 4; n++)
                    b[n] = *(const bf16x8*)&Bs[buf][(wc * 64 + n * 16 + lo) * 64 + ksl * 32 + hi * 8];
                #pragma unroll
                for (int m = 0; m < 4; m++)
                    #pragma unroll
                    for (int n = 0; n < 4; n++)
                        acc[m][n] = __builtin_amdgcn_mfma_f32_16x16x32_bf16(a[m], b[n], acc[m][n], 0, 0, 0);
            }
            __syncthreads();
        }

        // epilogue: C/D layout col=lane&15, row=(lane>>4)*4+reg  [m89]
        #pragma unroll
        for (int m = 0; m < 4; m++) {
            #pragma unroll
            for (int q = 0; q < 4; q++) {
                const int rl = wr * 64 + m * 16 + hi * 4 + q;
                const int grow = rowBase + rl;
                const float d = diag_s[rl];
                unsigned long long pk = 0ULL;
                int bmin = 0x7FFFFFFF;
                #pragma unroll
                for (int n = 0; n < 4; n++) {
                    const int gcol = colBase + wc * 64 + n * 16 + lo;
                    const float s = acc[m][n][q];
                    if (gcol != grow) {
                        unsigned u = __float_as_uint(s);
                        unsigned key = (u & 0x80000000u) ? ~u : (u | 0x80000000u);
                        unsigned long long p = ((unsigned long long)key << 32) | (unsigned)gcol;
                        pk = (p > pk) ? p : pk;
                        if (s > d - 0.5f && s < d - 0.2f) bmin = min(bmin, gcol);
                    }
                }
                #pragma unroll
                for (int off = 1; off < 16; off <<= 1) {
                    unsigned long long po = __shfl_xor(pk, off);
                    int bo = __shfl_xor(bmin, off);
                    pk = (po > pk) ? po : pk;
                    bmin = min(bmin, bo);
                }
                if (lo == 0) {
                    atomicMax(&fb_l[rl], pk);
                    if (bmin != 0x7FFFFFFF) atomicMin(&band_l[rl], bmin);
                }
            }
        }
        __syncthreads();   // epilogue atomics done before next ct staging overwrites nothing shared, but join anyway
    }

    if (tid < 128) {
        bandPart[colGroup * NB + rowBase + tid] = band_l[tid];
        fbPart[colGroup * NB + rowBase + tid] = fb_l[tid];
    }
}

// ---------------- combine partials ----------------
__global__ __launch_bounds__(256) void combine2_kernel(const int* __restrict__ bandPart,
                                                       const unsigned long long* __restrict__ fbPart,
                                                       int* __restrict__ neg) {
    int row = blockIdx.x * 256 + threadIdx.x;
    int bmin = 0x7FFFFFFF;
    unsigned long long pk = 0ULL;
    #pragma unroll
    for (int g = 0; g < 16; g++) {
        bmin = min(bmin, bandPart[g * NB + row]);
        unsigned long long f = fbPart[g * NB + row];
        pk = (f > pk) ? f : pk;
    }
    neg[row] = (bmin != 0x7FFFFFFF) ? bmin : (int)(unsigned)(pk & 0xFFFFFFFFull);
}

// ==================== fallback fp32 mining path (R2, proven) ====================
__global__ __launch_bounds__(256) void mine_kernel(const float* __restrict__ tuni,
                                                   const float* __restrict__ vuni,
                                                   const float* __restrict__ diag,
                                                   int* __restrict__ band_idx,
                                                   unsigned long long* __restrict__ fb) {
    __shared__ float Ts[64][68];
    __shared__ float Vs[64][68];
    __shared__ float diag_s[64];
    __shared__ int band_l[64];
    __shared__ unsigned long long fb_l[64];

    const int tid = threadIdx.x;
    const int rowBase = blockIdx.x * 64;
    const int colChunk = blockIdx.y;
    const int tx = tid & 15, ty = tid >> 4;

    if (tid < 64) {
        band_l[tid] = 0x7FFFFFFF;
        fb_l[tid] = 0ULL;
        diag_s[tid] = diag[rowBase + tid];
    }
    __syncthreads();

    for (int ct = 0; ct < 16; ++ct) {
        const int colBase = colChunk * 1024 + ct * 64;
        float acc[4][4];
        #pragma unroll
        for (int m = 0; m < 4; m++)
            #pragma unroll
            for (int n = 0; n < 4; n++) acc[m][n] = 0.f;

        for (int kc = 0; kc < DD; kc += 64) {
            __syncthreads();
            #pragma unroll
            for (int i = 0; i < 4; i++) {
                int idx = tid + i * 256;
                int r = idx >> 4, c = idx & 15;
                float4 tv = *(const float4*)(tuni + (size_t)(rowBase + r) * DD + kc + c * 4);
                *(float4*)&Ts[r][c * 4] = tv;
                float4 vv = *(const float4*)(vuni + (size_t)(colBase + r) * DD + kc + c * 4);
                *(float4*)&Vs[r][c * 4] = vv;
            }
            __syncthreads();
            #pragma unroll 4
            for (int kq = 0; kq < 16; kq++) {
                float4 tq[4], vq[4];
                #pragma unroll
                for (int m = 0; m < 4; m++) tq[m] = *(const float4*)&Ts[ty + 16 * m][kq * 4];
                #pragma unroll
                for (int n = 0; n < 4; n++) vq[n] = *(const float4*)&Vs[tx + 16 * n][kq * 4];
                #pragma unroll
                for (int m = 0; m < 4; m++)
                    #pragma unroll
                    for (int n = 0; n < 4; n++)
                        acc[m][n] += tq[m].x * vq[n].x + tq[m].y * vq[n].y +
                                     tq[m].z * vq[n].z + tq[m].w * vq[n].w;
            }
        }

        #pragma unroll
        for (int m = 0; m < 4; m++) {
            const int rl = ty + 16 * m;
            const int grow = rowBase + rl;
            const float d = diag_s[rl];
            unsigned long long pk = 0ULL;
            int bmin = 0x7FFFFFFF;
            #pragma unroll
            for (int n = 0; n < 4; n++) {
                int gcol = colBase + tx + 16 * n;
                float s = acc[m][n];
                if (gcol != grow) {
                    unsigned u = __float_as_uint(s);
                    unsigned key = (u & 0x80000000u) ? ~u : (u | 0x80000000u);
                    unsigned long long p = ((unsigned long long)key << 32) | (unsigned)gcol;
                    pk = (p > pk) ? p : pk;
                    if (s > d - 0.5f && s < d - 0.2f) bmin = min(bmin, gcol);
                }
            }
            #pragma unroll
            for (int off = 1; off < 16; off <<= 1) {
                unsigned long long po = __shfl_xor(pk, off);
                int bo = __shfl_xor(bmin, off);
                pk = (po > pk) ? po : pk;
                bmin = min(bmin, bo);
            }
            if (tx == 0) {
                atomicMax(&fb_l[rl], pk);
                if (bmin != 0x7FFFFFFF) atomicMin(&band_l[rl], bmin);
            }
        }
    }
    __syncthreads();
    if (tid < 64) {
        int grow = rowBase + tid;
        if (band_l[tid] != 0x7FFFFFFF) atomicMin(&band_idx[grow], band_l[tid]);
        atomicMax(&fb[grow], fb_l[tid]);
    }
}

__global__ __launch_bounds__(256) void combine_kernel(const int* __restrict__ band_idx,
                                                      const unsigned long long* __restrict__ fb,
                                                      int* __restrict__ neg) {
    int i = blockIdx.x * 256 + threadIdx.x;
    int b = band_idx[i];
    neg[i] = (b < NB) ? b : (int)(unsigned)(fb[i] & 0xFFFFFFFFull);
}

// ==================== fused ITM head (pos + neg) + loss ====================
__device__ __forceinline__ void fma4(float4& acc, const float4 wv, const float xs) {
    acc.x += wv.x * xs; acc.y += wv.y * xs; acc.z += wv.z * xs; acc.w += wv.w * xs;
}

__device__ __forceinline__ float rdot(float4 t, float4 a, float4 wv) {
    float h0 = fmaxf(t.x + a.x, 0.f);
    float h1 = fmaxf(t.y + a.y, 0.f);
    float h2 = fmaxf(t.z + a.z, 0.f);
    float h3 = fmaxf(t.w + a.w, 0.f);
    return h0 * wv.x + h1 * wv.y + h2 * wv.z + h3 * wv.w;
}

__global__ __launch_bounds__(256) void head_kernel(const float* __restrict__ tcross,
                                                   const float* __restrict__ vcross,
                                                   const int* __restrict__ neg,
                                                   const float* __restrict__ W1,
                                                   const float* __restrict__ b1,
                                                   const float* __restrict__ W2,
                                                   const float* __restrict__ b2,
                                                   float* __restrict__ acc_out) {
    __shared__ float tL[8][DD], vpL[8][DD], vnL[8][DD];
    __shared__ float dotp[8], dotn[8];

    const int tid = threadIdx.x;
    const int rowBase = blockIdx.x * 8;

    #pragma unroll
    for (int i = 0; i < 2; i++) {
        int idx = tid + i * 256;
        int r = idx >> 6, c = idx & 63;
        *(float4*)&tL[r][c * 4]  = *(const float4*)(tcross + (size_t)(rowBase + r) * DD + c * 4);
        *(float4*)&vpL[r][c * 4] = *(const float4*)(vcross + (size_t)(rowBase + r) * DD + c * 4);
        int nr = neg[rowBase + r];
        *(float4*)&vnL[r][c * 4] = *(const float4*)(vcross + (size_t)nr * DD + c * 4);
    }
    __syncthreads();

    const int lane = tid & 63;
    const int g = tid >> 6;

    #pragma unroll
    for (int rr = 0; rr < 2; rr++) {
        int r = g * 2 + rr;
        float4 a = *(const float4*)&tL[r][lane * 4];
        float4 p = *(const float4*)&vpL[r][lane * 4];
        float4 q = *(const float4*)&vnL[r][lane * 4];
        float sp = a.x * p.x + a.y * p.y + a.z * p.z + a.w * p.w;
        float sn = a.x * q.x + a.y * q.y + a.z * q.z + a.w * q.w;
        #pragma unroll
        for (int off = 32; off; off >>= 1) {
            sp += __shfl_down(sp, off);
            sn += __shfl_down(sn, off);
        }
        if (lane == 0) { dotp[r] = sp; dotn[r] = sn; }
    }
    __syncthreads();

    const int u = lane;
    const int r0 = g * 2, r1 = g * 2 + 1;
    float4 bq = *(const float4*)(b1 + 4 * u);
    float4 accT0 = bq, accT1 = bq;
    float4 aP0 = {0, 0, 0, 0}, aP1 = {0, 0, 0, 0}, aN0 = {0, 0, 0, 0}, aN1 = {0, 0, 0, 0};
    const float* W1u = W1 + 4 * u;

    #pragma unroll 4
    for (int k = 0; k < 256; k++) {
        float4 w4 = *(const float4*)(W1u + (size_t)k * DD);
        float x0 = tL[r0][k], x1 = tL[r1][k];
        fma4(accT0, w4, x0); fma4(accT1, w4, x1);
    }
    #pragma unroll 4
    for (int k = 0; k < 256; k++) {
        float4 w4 = *(const float4*)(W1u + (size_t)(256 + k) * DD);
        float p0 = vpL[r0][k], p1 = vpL[r1][k];
        float q0 = vnL[r0][k], q1 = vnL[r1][k];
        fma4(aP0, w4, p0); fma4(aP1, w4, p1);
        fma4(aN0, w4, q0); fma4(aN1, w4, q1);
    }
    {
        float4 w4 = *(const float4*)(W1u + (size_t)512 * DD);
        fma4(aP0, w4, dotp[r0]); fma4(aP1, w4, dotp[r1]);
        fma4(aN0, w4, dotn[r0]); fma4(aN1, w4, dotn[r1]);
    }

    float4 w2q = *(const float4*)(W2 + 4 * u);
    float pp0 = rdot(accT0, aP0, w2q);
    float pp1 = rdot(accT1, aP1, w2q);
    float pn0 = rdot(accT0, aN0, w2q);
    float pn1 = rdot(accT1, aN1, w2q);
    #pragma unroll
    for (int off = 32; off; off >>= 1) {
        pp0 += __shfl_down(pp0, off);
        pp1 += __shfl_down(pp1, off);
        pn0 += __shfl_down(pn0, off);
        pn1 += __shfl_down(pn1, off);
    }
    if (lane == 0) {
        float bb = b2[0];
        float lp0 = pp0 + bb, lp1 = pp1 + bb, ln0 = pn0 + bb, ln1 = pn1 + bb;
        float term = -logf(1.f / (1.f + expf(-lp0)) + 1e-8f)
                     -logf(1.f / (1.f + expf(-lp1)) + 1e-8f)
                     -logf(1.f / (1.f + expf(ln0)) + 1e-8f)
                     -logf(1.f / (1.f + expf(ln1)) + 1e-8f);
        atomicAdd(acc_out, term);
    }
}

__global__ void finalize_kernel(const float* __restrict__ acc, float* __restrict__ out) {
    out[0] = acc[0] * (1.0f / (2.0f * (float)NB));
}

// ==================== launch ====================
extern "C" void kernel_launch(void* const* d_in, const int* in_sizes, int n_in,
                              void* d_out, int out_size, void* d_ws, size_t ws_size,
                              hipStream_t stream) {
    const float* vcross = (const float*)d_in[0];
    const float* tcross = (const float*)d_in[1];
    const float* vuni   = (const float*)d_in[2];
    const float* tuni   = (const float*)d_in[3];
    const float* W1     = (const float*)d_in[4];
    const float* b1     = (const float*)d_in[5];
    const float* W2     = (const float*)d_in[6];
    const float* b2     = (const float*)d_in[7];

    char* ws = (char*)d_ws;
    float* diag = (float*)(ws);
    int* neg    = (int*)(ws + 32768);
    float* acc  = (float*)(ws + 65536);

    hipMemsetAsync(acc, 0, sizeof(float), stream);
    diag_kernel<<<NB / 4, 256, 0, stream>>>(tuni, vuni, diag);

    if (ws_size >= (size_t)WS_FAST_BYTES) {
        int* bandPart = (int*)(ws + 131072);
        unsigned long long* fbPart = (unsigned long long*)(ws + 655360);
        unsigned short* tb = (unsigned short*)(ws + 1703936);
        unsigned short* vb = (unsigned short*)(ws + 5898240);

        cvt_kernel<<<NB * DD / 8 / 256, 256, 0, stream>>>(tuni, tb);
        cvt_kernel<<<NB * DD / 8 / 256, 256, 0, stream>>>(vuni, vb);
        mine2_kernel<<<dim3(NB / 128, 16), 256, 0, stream>>>(tb, vb, diag, bandPart, fbPart);
        combine2_kernel<<<NB / 256, 256, 0, stream>>>(bandPart, fbPart, neg);
    } else {
        int* band = (int*)(ws + 131072);
        unsigned long long* fb = (unsigned long long*)(ws + 131072 + 32768);
        hipMemsetAsync(band, 0x7F, NB * sizeof(int), stream);
        hipMemsetAsync(fb, 0, NB * sizeof(unsigned long long), stream);
        mine_kernel<<<dim3(NB / 64, 8), 256, 0, stream>>>(tuni, vuni, diag, band, fb);
        combine_kernel<<<NB / 256, 256, 0, stream>>>(band, fb, neg);
    }

    head_kernel<<<NB / 8, 256, 0, stream>>>(tcross, vcross, neg, W1, b1, W2, b2, acc);
    finalize_kernel<<<1, 1, 0, stream>>>(acc, (float*)d_out);
}

// Round 4
// 162.255 us; speedup vs baseline: 4.6789x; 1.4710x over previous
//
#include <hip/hip_runtime.h>
#include <stdint.h>

#define NB 8192
#define DD 256

typedef __attribute__((ext_vector_type(8))) short bf16x8;
typedef __attribute__((ext_vector_type(4))) float f32x4;

// ==================== workspace layout (10092544 B, proven in R3) ====================
// diag     f32[8192]        @ 0
// neg      int[8192]        @ 32768
// acc      f32[1]           @ 65536
// bandPart int[16][8192]    @ 131072   (512 KB)  -- after combine2: w1t bf16[256][512] (256 KB)
// fbPart   u64[16][8192]    @ 655360   (1 MB)    -- after combine2: dotp f32[8192], dotn f32[8192]
// tb       bf16[8192][256]  @ 1703936  (4 MB)    -- after mine2: tcross bf16
// vb       bf16[8192][256]  @ 5898240  (4 MB)    -- after mine2: vcross bf16
#define WS_FAST_BYTES 10092544

// ---------------- diag kernel: diag[i] = t[i].v[i] (fp32) ----------------
__global__ __launch_bounds__(256) void diag_kernel(const float* __restrict__ t,
                                                   const float* __restrict__ v,
                                                   float* __restrict__ diag) {
    int row = blockIdx.x * 4 + (threadIdx.x >> 6);
    int lane = threadIdx.x & 63;
    float4 a = *(const float4*)(t + (size_t)row * DD + lane * 4);
    float4 b = *(const float4*)(v + (size_t)row * DD + lane * 4);
    float s = a.x * b.x + a.y * b.y + a.z * b.z + a.w * b.w;
    #pragma unroll
    for (int off = 32; off; off >>= 1) s += __shfl_down(s, off);
    if (lane == 0) diag[row] = s;
}

// ---------------- dots kernel: dotp[i]=t[i].v[i], dotn[i]=t[i].v[neg[i]] ----------------
__global__ __launch_bounds__(256) void dots_kernel(const float* __restrict__ t,
                                                   const float* __restrict__ v,
                                                   const int* __restrict__ neg,
                                                   float* __restrict__ dotp,
                                                   float* __restrict__ dotn) {
    int row = blockIdx.x * 4 + (threadIdx.x >> 6);
    int lane = threadIdx.x & 63;
    int nr = neg[row];
    float4 a = *(const float4*)(t + (size_t)row * DD + lane * 4);
    float4 b = *(const float4*)(v + (size_t)row * DD + lane * 4);
    float4 c = *(const float4*)(v + (size_t)nr * DD + lane * 4);
    float sp = a.x * b.x + a.y * b.y + a.z * b.z + a.w * b.w;
    float sn = a.x * c.x + a.y * c.y + a.z * c.z + a.w * c.w;
    #pragma unroll
    for (int off = 32; off; off >>= 1) {
        sp += __shfl_down(sp, off);
        sn += __shfl_down(sn, off);
    }
    if (lane == 0) { dotp[row] = sp; dotn[row] = sn; }
}

// ---------------- f32 -> bf16 convert (RNE) ----------------
__device__ __forceinline__ unsigned short f2bf(float x) {
    uint32_t u = __float_as_uint(x);
    return (unsigned short)((u + 0x7FFFu + ((u >> 16) & 1u)) >> 16);
}

__global__ __launch_bounds__(256) void cvt_kernel(const float* __restrict__ in,
                                                  unsigned short* __restrict__ out) {
    int i = blockIdx.x * 256 + threadIdx.x;      // 8 floats per thread
    const float4* p = (const float4*)(in + (size_t)i * 8);
    float4 x = p[0], y = p[1];
    uint4 o;
    o.x = (uint32_t)f2bf(x.x) | ((uint32_t)f2bf(x.y) << 16);
    o.y = (uint32_t)f2bf(x.z) | ((uint32_t)f2bf(x.w) << 16);
    o.z = (uint32_t)f2bf(y.x) | ((uint32_t)f2bf(y.y) << 16);
    o.w = (uint32_t)f2bf(y.z) | ((uint32_t)f2bf(y.w) << 16);
    *(uint4*)(out + (size_t)i * 8) = o;
}

// ---------------- W1 transpose+cvt: W1T[n][k] = bf16(W1[k][n]), k<512 ----------------
__global__ __launch_bounds__(256) void w1t_kernel(const float* __restrict__ W1,
                                                  unsigned short* __restrict__ W1T) {
    int k = blockIdx.x;                     // 0..511
    int n = threadIdx.x;                    // 0..255
    W1T[(size_t)n * 512 + k] = f2bf(W1[(size_t)k * DD + n]);
}

// ---------------- MFMA mining kernel (m97 structure, proven R3) ----------------
__device__ __forceinline__ void stage_tiles(const unsigned short* __restrict__ TB,
                                            const unsigned short* __restrict__ VB,
                                            unsigned short* As, unsigned short* Bs,
                                            int rowBase, int colBase, int kc, int tid) {
    #pragma unroll
    for (int i = 0; i < 4; ++i) {
        int idx = i * 256 + tid;              // 0..1023
        int r = idx >> 3, c8 = idx & 7;
        __builtin_amdgcn_global_load_lds(
            (const __attribute__((address_space(1))) uint32_t*)(TB + (size_t)(rowBase + r) * DD + kc + c8 * 8),
            (__attribute__((address_space(3))) uint32_t*)(As + idx * 8), 16, 0, 0);
        __builtin_amdgcn_global_load_lds(
            (const __attribute__((address_space(1))) uint32_t*)(VB + (size_t)(colBase + r) * DD + kc + c8 * 8),
            (__attribute__((address_space(3))) uint32_t*)(Bs + idx * 8), 16, 0, 0);
    }
}

__global__ __launch_bounds__(256) void mine2_kernel(const unsigned short* __restrict__ TB,
                                                    const unsigned short* __restrict__ VB,
                                                    const float* __restrict__ diag,
                                                    int* __restrict__ bandPart,
                                                    unsigned long long* __restrict__ fbPart) {
    __shared__ unsigned short As[2][128 * 64];
    __shared__ unsigned short Bs[2][128 * 64];
    __shared__ float diag_s[128];
    __shared__ int band_l[128];
    __shared__ unsigned long long fb_l[128];

    const int tid = threadIdx.x;
    const int rowBase = blockIdx.x * 128;
    const int colGroup = blockIdx.y;

    const int lane = tid & 63;
    const int wave = tid >> 6;
    const int wr = wave >> 1, wc = wave & 1;
    const int lo = lane & 15, hi = lane >> 4;

    if (tid < 128) {
        band_l[tid] = 0x7FFFFFFF;
        fb_l[tid] = 0ULL;
        diag_s[tid] = diag[rowBase + tid];
    }

    for (int ct = 0; ct < 4; ++ct) {
        const int colBase = colGroup * 512 + ct * 128;
        f32x4 acc[4][4];
        #pragma unroll
        for (int m = 0; m < 4; m++)
            #pragma unroll
            for (int n = 0; n < 4; n++) acc[m][n] = (f32x4){0.f, 0.f, 0.f, 0.f};

        stage_tiles(TB, VB, As[0], Bs[0], rowBase, colBase, 0, tid);
        __syncthreads();

        for (int kt = 0; kt < 4; ++kt) {
            const int buf = kt & 1;
            if (kt < 3)
                stage_tiles(TB, VB, As[buf ^ 1], Bs[buf ^ 1], rowBase, colBase, (kt + 1) * 64, tid);
            #pragma unroll
            for (int ksl = 0; ksl < 2; ksl++) {
                bf16x8 a[4], b[4];
                #pragma unroll
                for (int m = 0; m < 4; m++)
                    a[m] = *(const bf16x8*)&As[buf][(wr * 64 + m * 16 + lo) * 64 + ksl * 32 + hi * 8];
                #pragma unroll
                for (int n = 0; n < 4; n++)
                    b[n] = *(const bf16x8*)&Bs[buf][(wc * 64 + n * 16 + lo) * 64 + ksl * 32 + hi * 8];
                #pragma unroll
                for (int m = 0; m < 4; m++)
                    #pragma unroll
                    for (int n = 0; n < 4; n++)
                        acc[m][n] = __builtin_amdgcn_mfma_f32_16x16x32_bf16(a[m], b[n], acc[m][n], 0, 0, 0);
            }
            __syncthreads();
        }

        // epilogue: C/D layout col=lane&15, row=(lane>>4)*4+reg  [m89]
        #pragma unroll
        for (int m = 0; m < 4; m++) {
            #pragma unroll
            for (int q = 0; q < 4; q++) {
                const int rl = wr * 64 + m * 16 + hi * 4 + q;
                const int grow = rowBase + rl;
                const float d = diag_s[rl];
                unsigned long long pk = 0ULL;
                int bmin = 0x7FFFFFFF;
                #pragma unroll
                for (int n = 0; n < 4; n++) {
                    const int gcol = colBase + wc * 64 + n * 16 + lo;
                    const float s = acc[m][n][q];
                    if (gcol != grow) {
                        unsigned u = __float_as_uint(s);
                        unsigned key = (u & 0x80000000u) ? ~u : (u | 0x80000000u);
                        unsigned long long p = ((unsigned long long)key << 32) | (unsigned)gcol;
                        pk = (p > pk) ? p : pk;
                        if (s > d - 0.5f && s < d - 0.2f) bmin = min(bmin, gcol);
                    }
                }
                #pragma unroll
                for (int off = 1; off < 16; off <<= 1) {
                    unsigned long long po = __shfl_xor(pk, off);
                    int bo = __shfl_xor(bmin, off);
                    pk = (po > pk) ? po : pk;
                    bmin = min(bmin, bo);
                }
                if (lo == 0) {
                    atomicMax(&fb_l[rl], pk);
                    if (bmin != 0x7FFFFFFF) atomicMin(&band_l[rl], bmin);
                }
            }
        }
        __syncthreads();
    }

    if (tid < 128) {
        bandPart[colGroup * NB + rowBase + tid] = band_l[tid];
        fbPart[colGroup * NB + rowBase + tid] = fb_l[tid];
    }
}

// ---------------- combine partials ----------------
__global__ __launch_bounds__(256) void combine2_kernel(const int* __restrict__ bandPart,
                                                       const unsigned long long* __restrict__ fbPart,
                                                       int* __restrict__ neg) {
    int row = blockIdx.x * 256 + threadIdx.x;
    int bmin = 0x7FFFFFFF;
    unsigned long long pk = 0ULL;
    #pragma unroll
    for (int g = 0; g < 16; g++) {
        bmin = min(bmin, bandPart[g * NB + row]);
        unsigned long long f = fbPart[g * NB + row];
        pk = (f > pk) ? f : pk;
    }
    neg[row] = (bmin != 0x7FFFFFFF) ? bmin : (int)(unsigned)(pk & 0xFFFFFFFFull);
}

// ==================== MFMA ITM head ====================
// Block: 64 rows x 256 cols of H, K=512 ([t|v]). grid (128, 2): y=0 pos, y=1 neg.
// Epilogue fuses +b1 +dot*W1row512, relu, @W2, sigmoid-loss, atomicAdd.
__device__ __forceinline__ void stage_head(const unsigned short* __restrict__ TCB,
                                           const unsigned short* __restrict__ VCB,
                                           const int* __restrict__ neg, int isNeg,
                                           const unsigned short* __restrict__ W1T,
                                           unsigned short* As, unsigned short* Bs,
                                           int rowBase, int kc, int tid) {
    #pragma unroll
    for (int i = 0; i < 2; ++i) {                 // A: 64 rows x 64 k
        int idx = i * 256 + tid;                  // 0..511
        int r = idx >> 3, c8 = idx & 7;
        const unsigned short* src;
        if (kc < 256) {
            src = TCB + (size_t)(rowBase + r) * DD + kc + c8 * 8;
        } else {
            int rr = isNeg ? neg[rowBase + r] : (rowBase + r);
            src = VCB + (size_t)rr * DD + (kc - 256) + c8 * 8;
        }
        __builtin_amdgcn_global_load_lds(
            (const __attribute__((address_space(1))) uint32_t*)src,
            (__attribute__((address_space(3))) uint32_t*)(As + idx * 8), 16, 0, 0);
    }
    #pragma unroll
    for (int i = 0; i < 8; ++i) {                 // B: 256 cols x 64 k
        int idx = i * 256 + tid;                  // 0..2047
        int n = idx >> 3, c8 = idx & 7;
        __builtin_amdgcn_global_load_lds(
            (const __attribute__((address_space(1))) uint32_t*)(W1T + (size_t)n * 512 + kc + c8 * 8),
            (__attribute__((address_space(3))) uint32_t*)(Bs + idx * 8), 16, 0, 0);
    }
}

__global__ __launch_bounds__(256) void head2_kernel(const unsigned short* __restrict__ TCB,
                                                    const unsigned short* __restrict__ VCB,
                                                    const unsigned short* __restrict__ W1T,
                                                    const int* __restrict__ neg,
                                                    const float* __restrict__ dotp,
                                                    const float* __restrict__ dotn,
                                                    const float* __restrict__ W1,
                                                    const float* __restrict__ b1,
                                                    const float* __restrict__ W2,
                                                    const float* __restrict__ b2,
                                                    float* __restrict__ acc_out) {
    __shared__ unsigned short As[2][64 * 64];     // 8 KB x2
    __shared__ unsigned short Bs[2][256 * 64];    // 32 KB x2
    __shared__ float dot_l[64];
    __shared__ float logit_l[64];

    const int tid = threadIdx.x;
    const int rowBase = blockIdx.x * 64;
    const int isNeg = blockIdx.y;

    const int lane = tid & 63;
    const int wc = tid >> 6;                      // wave = col group (4 x 64 cols)
    const int lo = lane & 15, hi = lane >> 4;

    if (tid < 64) {
        const float* dsrc = isNeg ? dotn : dotp;
        dot_l[tid] = dsrc[rowBase + tid];
        logit_l[tid] = 0.f;
    }

    f32x4 acc[4][4];
    #pragma unroll
    for (int m = 0; m < 4; m++)
        #pragma unroll
        for (int n = 0; n < 4; n++) acc[m][n] = (f32x4){0.f, 0.f, 0.f, 0.f};

    stage_head(TCB, VCB, neg, isNeg, W1T, As[0], Bs[0], rowBase, 0, tid);
    __syncthreads();

    for (int kt = 0; kt < 8; ++kt) {
        const int buf = kt & 1;
        if (kt < 7)
            stage_head(TCB, VCB, neg, isNeg, W1T, As[buf ^ 1], Bs[buf ^ 1], rowBase, (kt + 1) * 64, tid);
        #pragma unroll
        for (int ksl = 0; ksl < 2; ksl++) {
            bf16x8 a[4], b[4];
            #pragma unroll
            for (int m = 0; m < 4; m++)
                a[m] = *(const bf16x8*)&As[buf][(m * 16 + lo) * 64 + ksl * 32 + hi * 8];
            #pragma unroll
            for (int n = 0; n < 4; n++)
                b[n] = *(const bf16x8*)&Bs[buf][(wc * 64 + n * 16 + lo) * 64 + ksl * 32 + hi * 8];
            #pragma unroll
            for (int m = 0; m < 4; m++)
                #pragma unroll
                for (int n = 0; n < 4; n++)
                    acc[m][n] = __builtin_amdgcn_mfma_f32_16x16x32_bf16(a[m], b[n], acc[m][n], 0, 0, 0);
        }
        __syncthreads();
    }

    // epilogue: per-lane cols cl = wc*64 + n*16 + lo (n=0..3), rows rl = m*16 + hi*4 + q
    float b1v[4], w5v[4], w2v[4];
    #pragma unroll
    for (int n = 0; n < 4; n++) {
        int cl = wc * 64 + n * 16 + lo;
        b1v[n] = b1[cl];
        w5v[n] = W1[(size_t)512 * DD + cl];
        w2v[n] = W2[cl];
    }
    #pragma unroll
    for (int m = 0; m < 4; m++) {
        #pragma unroll
        for (int q = 0; q < 4; q++) {
            const int rl = m * 16 + hi * 4 + q;
            const float dt = dot_l[rl];
            float x = 0.f;
            #pragma unroll
            for (int n = 0; n < 4; n++) {
                float h = acc[m][n][q] + b1v[n] + dt * w5v[n];
                x += fmaxf(h, 0.f) * w2v[n];
            }
            #pragma unroll
            for (int off = 1; off < 16; off <<= 1) x += __shfl_xor(x, off);
            if (lo == 0) atomicAdd(&logit_l[rl], x);
        }
    }
    __syncthreads();

    if (tid < 64) {
        float x = logit_l[tid] + b2[0];
        // pos: -log(sigmoid(x)+eps); neg: -log(sigmoid(-x)+eps)
        float z = isNeg ? x : -x;
        float term = -logf(1.f / (1.f + expf(z)) + 1e-8f);
        #pragma unroll
        for (int off = 32; off; off >>= 1) term += __shfl_down(term, off);
        if (tid == 0) atomicAdd(acc_out, term);
    }
}

// ==================== fallback fp32 path (R2, proven) ====================
__global__ __launch_bounds__(256) void mine_kernel(const float* __restrict__ tuni,
                                                   const float* __restrict__ vuni,
                                                   const float* __restrict__ diag,
                                                   int* __restrict__ band_idx,
                                                   unsigned long long* __restrict__ fb) {
    __shared__ float Ts[64][68];
    __shared__ float Vs[64][68];
    __shared__ float diag_s[64];
    __shared__ int band_l[64];
    __shared__ unsigned long long fb_l[64];

    const int tid = threadIdx.x;
    const int rowBase = blockIdx.x * 64;
    const int colChunk = blockIdx.y;
    const int tx = tid & 15, ty = tid >> 4;

    if (tid < 64) {
        band_l[tid] = 0x7FFFFFFF;
        fb_l[tid] = 0ULL;
        diag_s[tid] = diag[rowBase + tid];
    }
    __syncthreads();

    for (int ct = 0; ct < 16; ++ct) {
        const int colBase = colChunk * 1024 + ct * 64;
        float acc[4][4];
        #pragma unroll
        for (int m = 0; m < 4; m++)
            #pragma unroll
            for (int n = 0; n < 4; n++) acc[m][n] = 0.f;

        for (int kc = 0; kc < DD; kc += 64) {
            __syncthreads();
            #pragma unroll
            for (int i = 0; i < 4; i++) {
                int idx = tid + i * 256;
                int r = idx >> 4, c = idx & 15;
                float4 tv = *(const float4*)(tuni + (size_t)(rowBase + r) * DD + kc + c * 4);
                *(float4*)&Ts[r][c * 4] = tv;
                float4 vv = *(const float4*)(vuni + (size_t)(colBase + r) * DD + kc + c * 4);
                *(float4*)&Vs[r][c * 4] = vv;
            }
            __syncthreads();
            #pragma unroll 4
            for (int kq = 0; kq < 16; kq++) {
                float4 tq[4], vq[4];
                #pragma unroll
                for (int m = 0; m < 4; m++) tq[m] = *(const float4*)&Ts[ty + 16 * m][kq * 4];
                #pragma unroll
                for (int n = 0; n < 4; n++) vq[n] = *(const float4*)&Vs[tx + 16 * n][kq * 4];
                #pragma unroll
                for (int m = 0; m < 4; m++)
                    #pragma unroll
                    for (int n = 0; n < 4; n++)
                        acc[m][n] += tq[m].x * vq[n].x + tq[m].y * vq[n].y +
                                     tq[m].z * vq[n].z + tq[m].w * vq[n].w;
            }
        }

        #pragma unroll
        for (int m = 0; m < 4; m++) {
            const int rl = ty + 16 * m;
            const int grow = rowBase + rl;
            const float d = diag_s[rl];
            unsigned long long pk = 0ULL;
            int bmin = 0x7FFFFFFF;
            #pragma unroll
            for (int n = 0; n < 4; n++) {
                int gcol = colBase + tx + 16 * n;
                float s = acc[m][n];
                if (gcol != grow) {
                    unsigned u = __float_as_uint(s);
                    unsigned key = (u & 0x80000000u) ? ~u : (u | 0x80000000u);
                    unsigned long long p = ((unsigned long long)key << 32) | (unsigned)gcol;
                    pk = (p > pk) ? p : pk;
                    if (s > d - 0.5f && s < d - 0.2f) bmin = min(bmin, gcol);
                }
            }
            #pragma unroll
            for (int off = 1; off < 16; off <<= 1) {
                unsigned long long po = __shfl_xor(pk, off);
                int bo = __shfl_xor(bmin, off);
                pk = (po > pk) ? po : pk;
                bmin = min(bmin, bo);
            }
            if (tx == 0) {
                atomicMax(&fb_l[rl], pk);
                if (bmin != 0x7FFFFFFF) atomicMin(&band_l[rl], bmin);
            }
        }
    }
    __syncthreads();
    if (tid < 64) {
        int grow = rowBase + tid;
        if (band_l[tid] != 0x7FFFFFFF) atomicMin(&band_idx[grow], band_l[tid]);
        atomicMax(&fb[grow], fb_l[tid]);
    }
}

__global__ __launch_bounds__(256) void combine_kernel(const int* __restrict__ band_idx,
                                                      const unsigned long long* __restrict__ fb,
                                                      int* __restrict__ neg) {
    int i = blockIdx.x * 256 + threadIdx.x;
    int b = band_idx[i];
    neg[i] = (b < NB) ? b : (int)(unsigned)(fb[i] & 0xFFFFFFFFull);
}

__device__ __forceinline__ void fma4(float4& acc, const float4 wv, const float xs) {
    acc.x += wv.x * xs; acc.y += wv.y * xs; acc.z += wv.z * xs; acc.w += wv.w * xs;
}

__device__ __forceinline__ float rdot(float4 t, float4 a, float4 wv) {
    float h0 = fmaxf(t.x + a.x, 0.f);
    float h1 = fmaxf(t.y + a.y, 0.f);
    float h2 = fmaxf(t.z + a.z, 0.f);
    float h3 = fmaxf(t.w + a.w, 0.f);
    return h0 * wv.x + h1 * wv.y + h2 * wv.z + h3 * wv.w;
}

__global__ __launch_bounds__(256) void head_kernel(const float* __restrict__ tcross,
                                                   const float* __restrict__ vcross,
                                                   const int* __restrict__ neg,
                                                   const float* __restrict__ W1,
                                                   const float* __restrict__ b1,
                                                   const float* __restrict__ W2,
                                                   const float* __restrict__ b2,
                                                   float* __restrict__ acc_out) {
    __shared__ float tL[8][DD], vpL[8][DD], vnL[8][DD];
    __shared__ float dotp[8], dotn[8];

    const int tid = threadIdx.x;
    const int rowBase = blockIdx.x * 8;

    #pragma unroll
    for (int i = 0; i < 2; i++) {
        int idx = tid + i * 256;
        int r = idx >> 6, c = idx & 63;
        *(float4*)&tL[r][c * 4]  = *(const float4*)(tcross + (size_t)(rowBase + r) * DD + c * 4);
        *(float4*)&vpL[r][c * 4] = *(const float4*)(vcross + (size_t)(rowBase + r) * DD + c * 4);
        int nr = neg[rowBase + r];
        *(float4*)&vnL[r][c * 4] = *(const float4*)(vcross + (size_t)nr * DD + c * 4);
    }
    __syncthreads();

    const int lane = tid & 63;
    const int g = tid >> 6;

    #pragma unroll
    for (int rr = 0; rr < 2; rr++) {
        int r = g * 2 + rr;
        float4 a = *(const float4*)&tL[r][lane * 4];
        float4 p = *(const float4*)&vpL[r][lane * 4];
        float4 q = *(const float4*)&vnL[r][lane * 4];
        float sp = a.x * p.x + a.y * p.y + a.z * p.z + a.w * p.w;
        float sn = a.x * q.x + a.y * q.y + a.z * q.z + a.w * q.w;
        #pragma unroll
        for (int off = 32; off; off >>= 1) {
            sp += __shfl_down(sp, off);
            sn += __shfl_down(sn, off);
        }
        if (lane == 0) { dotp[r] = sp; dotn[r] = sn; }
    }
    __syncthreads();

    const int u = lane;
    const int r0 = g * 2, r1 = g * 2 + 1;
    float4 bq = *(const float4*)(b1 + 4 * u);
    float4 accT0 = bq, accT1 = bq;
    float4 aP0 = {0, 0, 0, 0}, aP1 = {0, 0, 0, 0}, aN0 = {0, 0, 0, 0}, aN1 = {0, 0, 0, 0};
    const float* W1u = W1 + 4 * u;

    #pragma unroll 4
    for (int k = 0; k < 256; k++) {
        float4 w4 = *(const float4*)(W1u + (size_t)k * DD);
        float x0 = tL[r0][k], x1 = tL[r1][k];
        fma4(accT0, w4, x0); fma4(accT1, w4, x1);
    }
    #pragma unroll 4
    for (int k = 0; k < 256; k++) {
        float4 w4 = *(const float4*)(W1u + (size_t)(256 + k) * DD);
        float p0 = vpL[r0][k], p1 = vpL[r1][k];
        float q0 = vnL[r0][k], q1 = vnL[r1][k];
        fma4(aP0, w4, p0); fma4(aP1, w4, p1);
        fma4(aN0, w4, q0); fma4(aN1, w4, q1);
    }
    {
        float4 w4 = *(const float4*)(W1u + (size_t)512 * DD);
        fma4(aP0, w4, dotp[r0]); fma4(aP1, w4, dotp[r1]);
        fma4(aN0, w4, dotn[r0]); fma4(aN1, w4, dotn[r1]);
    }

    float4 w2q = *(const float4*)(W2 + 4 * u);
    float pp0 = rdot(accT0, aP0, w2q);
    float pp1 = rdot(accT1, aP1, w2q);
    float pn0 = rdot(accT0, aN0, w2q);
    float pn1 = rdot(accT1, aN1, w2q);
    #pragma unroll
    for (int off = 32; off; off >>= 1) {
        pp0 += __shfl_down(pp0, off);
        pp1 += __shfl_down(pp1, off);
        pn0 += __shfl_down(pn0, off);
        pn1 += __shfl_down(pn1, off);
    }
    if (lane == 0) {
        float bb = b2[0];
        float lp0 = pp0 + bb, lp1 = pp1 + bb, ln0 = pn0 + bb, ln1 = pn1 + bb;
        float term = -logf(1.f / (1.f + expf(-lp0)) + 1e-8f)
                     -logf(1.f / (1.f + expf(-lp1)) + 1e-8f)
                     -logf(1.f / (1.f + expf(ln0)) + 1e-8f)
                     -logf(1.f / (1.f + expf(ln1)) + 1e-8f);
        atomicAdd(acc_out, term);
    }
}

__global__ void finalize_kernel(const float* __restrict__ acc, float* __restrict__ out) {
    out[0] = acc[0] * (1.0f / (2.0f * (float)NB));
}

// ==================== launch ====================
extern "C" void kernel_launch(void* const* d_in, const int* in_sizes, int n_in,
                              void* d_out, int out_size, void* d_ws, size_t ws_size,
                              hipStream_t stream) {
    const float* vcross = (const float*)d_in[0];
    const float* tcross = (const float*)d_in[1];
    const float* vuni   = (const float*)d_in[2];
    const float* tuni   = (const float*)d_in[3];
    const float* W1     = (const float*)d_in[4];
    const float* b1     = (const float*)d_in[5];
    const float* W2     = (const float*)d_in[6];
    const float* b2     = (const float*)d_in[7];

    char* ws = (char*)d_ws;
    float* diag = (float*)(ws);
    int* neg    = (int*)(ws + 32768);
    float* acc  = (float*)(ws + 65536);

    hipMemsetAsync(acc, 0, sizeof(float), stream);
    diag_kernel<<<NB / 4, 256, 0, stream>>>(tuni, vuni, diag);

    if (ws_size >= (size_t)WS_FAST_BYTES) {
        int* bandPart = (int*)(ws + 131072);
        unsigned long long* fbPart = (unsigned long long*)(ws + 655360);
        unsigned short* tb = (unsigned short*)(ws + 1703936);
        unsigned short* vb = (unsigned short*)(ws + 5898240);
        // aliases valid after combine2:
        unsigned short* w1t = (unsigned short*)(ws + 131072);   // over bandPart
        float* dotp = (float*)(ws + 655360);                    // over fbPart
        float* dotn = (float*)(ws + 655360 + 32768);

        // mining (bf16 MFMA)
        cvt_kernel<<<NB * DD / 8 / 256, 256, 0, stream>>>(tuni, tb);
        cvt_kernel<<<NB * DD / 8 / 256, 256, 0, stream>>>(vuni, vb);
        mine2_kernel<<<dim3(NB / 128, 16), 256, 0, stream>>>(tb, vb, diag, bandPart, fbPart);
        combine2_kernel<<<NB / 256, 256, 0, stream>>>(bandPart, fbPart, neg);

        // head prep (reuses freed regions; stream order guarantees safety)
        w1t_kernel<<<512, 256, 0, stream>>>(W1, w1t);
        cvt_kernel<<<NB * DD / 8 / 256, 256, 0, stream>>>(tcross, tb);   // tb := tcross bf16
        cvt_kernel<<<NB * DD / 8 / 256, 256, 0, stream>>>(vcross, vb);   // vb := vcross bf16
        dots_kernel<<<NB / 4, 256, 0, stream>>>(tcross, vcross, neg, dotp, dotn);

        head2_kernel<<<dim3(NB / 64, 2), 256, 0, stream>>>(tb, vb, w1t, neg, dotp, dotn,
                                                           W1, b1, W2, b2, acc);
    } else {
        int* band = (int*)(ws + 131072);
        unsigned long long* fb = (unsigned long long*)(ws + 131072 + 32768);
        hipMemsetAsync(band, 0x7F, NB * sizeof(int), stream);
        hipMemsetAsync(fb, 0, NB * sizeof(unsigned long long), stream);
        mine_kernel<<<dim3(NB / 64, 8), 256, 0, stream>>>(tuni, vuni, diag, band, fb);
        combine_kernel<<<NB / 256, 256, 0, stream>>>(band, fb, neg);
        head_kernel<<<NB / 8, 256, 0, stream>>>(tcross, vcross, neg, W1, b1, W2, b2, acc);
    }

    finalize_kernel<<<1, 1, 0, stream>>>(acc, (float*)d_out);
}